// Round 9
// baseline (253.856 us; speedup 1.0000x reference)
//
#include <hip/hip_runtime.h>
#include <cmath>
#include <cstring>

#define NUM_S   64
#define IMG_H   256
#define IMG_W   256
#define HWSZ    (IMG_H*IMG_W)          // 65536
#define BATCH   2
#define NPIX    (BATCH*HWSZ)           // 131072
#define NEL     (BATCH*NUM_S*HWSZ)     // 8388608
#define NSLICE  (BATCH*NUM_S)          // 128
#define VALID   246
#define EPS_F   1e-20f
#define C1_F    1e-4f
#define C2_F    9e-4f
#define RS      264                    // V_lds row stride (halves); 132 dw = 4 mod 32
#define FS      (16*RS)                // field size in halves = 4224

typedef __fp16 half8  __attribute__((ext_vector_type(8)));
typedef __fp16 fp16x2 __attribute__((ext_vector_type(2)));
using fragC = __attribute__((ext_vector_type(4))) float;  // 4 fp32

union H8 { half8 v; short s[8]; int i[4]; };
union PK { fp16x2 v; int i; };
union HS { __fp16 f; short s; };

struct GH { short h[11]; };            // fp16 bits of gaussian taps (sum ~= 1)

__device__ inline fp16x2 pkrtz(float a, float b) {
    return __builtin_amdgcn_cvt_pkrtz(a, b);   // 1 instr packs 2 values
}
__device__ inline float frcp(float x)  { return __builtin_amdgcn_rcpf(x); }
__device__ inline float flog2(float x) { return __builtin_amdgcn_logf(x); }   // v_log_f32
__device__ inline float fexp2(float x) { return __builtin_amdgcn_exp2f(x); }  // v_exp_f32

__device__ inline void block_atomic_add(float v, double* dst) {
    __shared__ float sm[8];
    __syncthreads();
    #pragma unroll
    for (int off = 32; off; off >>= 1) v += __shfl_down(v, off, 64);
    int lane = threadIdx.x & 63, w = threadIdx.x >> 6;
    if (lane == 0) sm[w] = v;
    __syncthreads();
    if (threadIdx.x == 0) {
        double s = 0.0;
        int nw = blockDim.x >> 6;
        for (int i = 0; i < nw; ++i) s += (double)sm[i];
        atomicAdd(dst, s);
    }
}

// Kernel 1: per-pixel softmax-prefix scan. 1 px/thread (1024 blocks -> 16
// waves/CU: R8 was latency-bound at 8), depth-2 prefetch. No online max
// (e<=2e15, den<=1.3e17 fit fp32). Stores packed fp16 {p(lo), cummax(hi)}
// as one dword -- halves write traffic, and ssim consumes fp16 anyway.
__global__ __launch_bounds__(256) void scan_kernel(
    const float* __restrict__ img, const float* __restrict__ tgt,
    const float* __restrict__ un,
    unsigned* __restrict__ pt1, unsigned* __restrict__ pt2,
    double* __restrict__ acc)
{
    int tid = blockIdx.x * 256 + threadIdx.x;
    bool bwd = tid >= NPIX;                  // uniform per block
    int pix = bwd ? tid - NPIX : tid;
    int b = pix >> 16, hw = pix & (HWSZ - 1);
    int idx  = b * (NUM_S * HWSZ) + hw + (bwd ? (NUM_S - 1) * HWSZ : 0);
    int step = bwd ? -HWSZ : HWSZ;
    unsigned* __restrict__ out = bwd ? pt2 : pt1;

    float num = 0.f, den = 0.f, tm = -INFINITY, l1x = 0.f, l1p = 0.f;

    float x0 = img[idx], u0 = un[idx], t0 = tgt[idx];
    int i1 = idx + step;
    float x1 = img[i1], u1 = un[i1], t1 = tgt[i1];

    #pragma unroll 2
    for (int i = 0; i < NUM_S; ++i) {
        float x2 = 0.f, u2 = 0.f, t2 = 0.f;
        if (i + 2 < NUM_S) {
            int i2 = idx + 2 * step;
            x2 = img[i2]; u2 = un[i2]; t2 = tgt[i2];
        }
        // w = eps - ln(u+eps) > 0;  e = exp(2x) * w^-2
        float w = fmaf(flog2(u0 + EPS_F), -0.6931471805599453f, EPS_F);
        float r = frcp(w);
        float e = fexp2(x0 * 2.8853900817779268f) * (r * r);
        num = fmaf(e, x0, num);
        den += e;
        float p = num * frcp(den);
        tm = fmaxf(tm, t0);
        if (!bwd) l1x += fabsf(x0 - t0);
        l1p += fabsf(p - tm);
        PK pk; pk.v = pkrtz(p, tm);
        out[idx] = (unsigned)pk.i;
        idx += step;
        x0 = x1; u0 = u1; t0 = t1;
        x1 = x2; u1 = u2; t1 = t2;
    }
    block_atomic_add(l1x, &acc[0]);
    block_atomic_add(l1p, bwd ? &acc[2] : &acc[1]);
}

// Kernel 2: MFMA separable-Gaussian SSIM, fp16 fragments.
// Stage 1: D16x16 = band(16x32) . B(field tile); cross-tile double-buffered
// global loads (latency was the R8 binder, not VALU). Pairs 1/2 read packed
// fp16 {p,t} (4 B/px): fragments by bitfield merge + v_pk_mul_f16 squares.
// V -> LDS fp16, RS=264 (132 dw == 4 mod 32: stage-2 b128 reads 2-way free,
// stage-1 writes 4-way). Pad cols [256,264) zeroed; last-tile overreach
// clamped (garbage meets band-zero weights / masked outputs only).
__global__ __launch_bounds__(256) void ssim_kernel(
    const float* __restrict__ img, const float* __restrict__ tgt,
    const unsigned* __restrict__ pt1, const unsigned* __restrict__ pt2,
    GH gh, double* __restrict__ acc)
{
    __shared__ short Vl[5][FS];            // 42240 B
    int pair  = blockIdx.z;
    int base  = blockIdx.y * HWSZ;
    int r0    = blockIdx.x * 16;
    int lane  = threadIdx.x & 63;
    int wid   = threadIdx.x >> 6;          // 0..3
    int q     = lane >> 4;                 // 0..3
    int n     = lane & 15;

    // band fragment: g[(q*8+j)-n], zero outside. A in stage 1, B in stage 2.
    H8 band;
    #pragma unroll
    for (int j = 0; j < 8; ++j) {
        int kk = q * 8 + j - n;
        short hv = 0;
        #pragma unroll
        for (int w = 0; w < 11; ++w) hv = (kk == w) ? gh.h[w] : hv;
        band.s[j] = hv;
    }

    // zero pad cols [256,264): 5 fields x 16 rows x 4 dwords = 320 dwords
    for (int d = threadIdx.x; d < 320; d += 256) {
        int f = d >> 6, rm = d & 63, r = rm >> 2, cc = rm & 3;
        ((int*)Vl)[f * 2112 + r * 132 + 128 + cc] = 0;
    }

    bool clampR = (r0 == 240);
    const fragC zero = {0.f, 0.f, 0.f, 0.f};

    // ---- stage 1: 4 c-tiles per wave, double-buffered loads ----
    if (pair == 0) {
        float xa[8], ya[8], xb[8], yb[8];
        auto loadA = [&](int it, float* xr, float* yr) {
            int col = (wid * 4 + it) * 16 + n;
            if (!clampR) {
                const float* px = img + base + (r0 + q * 8) * IMG_W + col;
                const float* py = tgt + base + (r0 + q * 8) * IMG_W + col;
                #pragma unroll
                for (int j = 0; j < 8; ++j) { xr[j] = px[j * IMG_W]; yr[j] = py[j * IMG_W]; }
            } else {
                #pragma unroll
                for (int j = 0; j < 8; ++j) {
                    int rr = min(r0 + q * 8 + j, IMG_H - 1);
                    xr[j] = img[base + rr * IMG_W + col];
                    yr[j] = tgt[base + rr * IMG_W + col];
                }
            }
        };
        loadA(0, xa, ya);
        #pragma unroll
        for (int it = 0; it < 4; ++it) {
            float* cx = (it & 1) ? xb : xa;
            float* cy = (it & 1) ? yb : ya;
            if (it < 3) loadA(it + 1, (it & 1) ? xa : xb, (it & 1) ? ya : yb);
            H8 fX, fY, fXX, fYY, fXY;
            #pragma unroll
            for (int j = 0; j < 4; ++j) {
                PK a;
                a.v = pkrtz(cx[2*j], cx[2*j+1]); fX.i[j] = a.i;
                a.v = pkrtz(cy[2*j], cy[2*j+1]); fY.i[j] = a.i;
            }
            fXX.v = fX.v * fX.v;               // v_pk_mul_f16
            fYY.v = fY.v * fY.v;
            fXY.v = fX.v * fY.v;
            fragC v0 = __builtin_amdgcn_mfma_f32_16x16x32_f16(band.v, fX.v,  zero, 0, 0, 0);
            fragC v1 = __builtin_amdgcn_mfma_f32_16x16x32_f16(band.v, fY.v,  zero, 0, 0, 0);
            fragC v2 = __builtin_amdgcn_mfma_f32_16x16x32_f16(band.v, fXX.v, zero, 0, 0, 0);
            fragC v3 = __builtin_amdgcn_mfma_f32_16x16x32_f16(band.v, fYY.v, zero, 0, 0, 0);
            fragC v4 = __builtin_amdgcn_mfma_f32_16x16x32_f16(band.v, fXY.v, zero, 0, 0, 0);
            int col = (wid * 4 + it) * 16 + n;
            #pragma unroll
            for (int reg = 0; reg < 4; ++reg) {
                int ro = (q * 4 + reg) * RS + col;
                HS cv;
                cv.f = (__fp16)v0[reg]; Vl[0][ro] = cv.s;
                cv.f = (__fp16)v1[reg]; Vl[1][ro] = cv.s;
                cv.f = (__fp16)v2[reg]; Vl[2][ro] = cv.s;
                cv.f = (__fp16)v3[reg]; Vl[3][ro] = cv.s;
                cv.f = (__fp16)v4[reg]; Vl[4][ro] = cv.s;
            }
        }
    } else {
        const unsigned* __restrict__ pp = (pair == 1 ? pt1 : pt2) + base;
        unsigned pa[8], pb[8];
        auto loadB = [&](int it, unsigned* pr) {
            int col = (wid * 4 + it) * 16 + n;
            if (!clampR) {
                const unsigned* p0 = pp + (r0 + q * 8) * IMG_W + col;
                #pragma unroll
                for (int j = 0; j < 8; ++j) pr[j] = p0[j * IMG_W];
            } else {
                #pragma unroll
                for (int j = 0; j < 8; ++j) {
                    int rr = min(r0 + q * 8 + j, IMG_H - 1);
                    pr[j] = pp[rr * IMG_W + col];
                }
            }
        };
        loadB(0, pa);
        #pragma unroll
        for (int it = 0; it < 4; ++it) {
            unsigned* cp = (it & 1) ? pb : pa;
            if (it < 3) loadB(it + 1, (it & 1) ? pa : pb);
            H8 fX, fY, fXX, fYY, fXY;
            #pragma unroll
            for (int j = 0; j < 4; ++j) {          // {p(lo), t(hi)} merge
                unsigned a = cp[2*j], b = cp[2*j+1];
                fX.i[j] = (int)((a & 0xffffu) | (b << 16));
                fY.i[j] = (int)((a >> 16) | (b & 0xffff0000u));
            }
            fXX.v = fX.v * fX.v;
            fYY.v = fY.v * fY.v;
            fXY.v = fX.v * fY.v;
            fragC v0 = __builtin_amdgcn_mfma_f32_16x16x32_f16(band.v, fX.v,  zero, 0, 0, 0);
            fragC v1 = __builtin_amdgcn_mfma_f32_16x16x32_f16(band.v, fY.v,  zero, 0, 0, 0);
            fragC v2 = __builtin_amdgcn_mfma_f32_16x16x32_f16(band.v, fXX.v, zero, 0, 0, 0);
            fragC v3 = __builtin_amdgcn_mfma_f32_16x16x32_f16(band.v, fYY.v, zero, 0, 0, 0);
            fragC v4 = __builtin_amdgcn_mfma_f32_16x16x32_f16(band.v, fXY.v, zero, 0, 0, 0);
            int col = (wid * 4 + it) * 16 + n;
            #pragma unroll
            for (int reg = 0; reg < 4; ++reg) {
                int ro = (q * 4 + reg) * RS + col;
                HS cv;
                cv.f = (__fp16)v0[reg]; Vl[0][ro] = cv.s;
                cv.f = (__fp16)v1[reg]; Vl[1][ro] = cv.s;
                cv.f = (__fp16)v2[reg]; Vl[2][ro] = cv.s;
                cv.f = (__fp16)v3[reg]; Vl[3][ro] = cv.s;
                cv.f = (__fp16)v4[reg]; Vl[4][ro] = cv.s;
            }
        }
    }
    __syncthreads();

    // ---- stage 2 + epilogue ----
    float lsum = 0.f;
    for (int it = 0; it < 4; ++it) {
        int c0 = (wid * 4 + it) * 16;
        int so = n * RS + c0 + q * 8;
        so = min(so, FS - 8);              // overreach only hits weight-zero k
        H8 a0, a1, a2, a3, a4;
        *(int4*)a0.i = *(const int4*)&Vl[0][so];
        *(int4*)a1.i = *(const int4*)&Vl[1][so];
        *(int4*)a2.i = *(const int4*)&Vl[2][so];
        *(int4*)a3.i = *(const int4*)&Vl[3][so];
        *(int4*)a4.i = *(const int4*)&Vl[4][so];
        fragC o0 = __builtin_amdgcn_mfma_f32_16x16x32_f16(a0.v, band.v, zero, 0, 0, 0);
        fragC o1 = __builtin_amdgcn_mfma_f32_16x16x32_f16(a1.v, band.v, zero, 0, 0, 0);
        fragC o2 = __builtin_amdgcn_mfma_f32_16x16x32_f16(a2.v, band.v, zero, 0, 0, 0);
        fragC o3 = __builtin_amdgcn_mfma_f32_16x16x32_f16(a3.v, band.v, zero, 0, 0, 0);
        fragC o4 = __builtin_amdgcn_mfma_f32_16x16x32_f16(a4.v, band.v, zero, 0, 0, 0);
        #pragma unroll
        for (int reg = 0; reg < 4; ++reg) {
            int r = r0 + q * 4 + reg;
            int c = c0 + n;
            if (r < VALID && c < VALID) {
                float m1 = o0[reg], m2 = o1[reg];
                float s11 = o2[reg] - m1 * m1;
                float s22 = o3[reg] - m2 * m2;
                float s12 = o4[reg] - m1 * m2;
                float nv = (2.f * m1 * m2 + C1_F) * (2.f * s12 + C2_F);
                float dv = (m1 * m1 + m2 * m2 + C1_F) * (s11 + s22 + C2_F);
                lsum += nv * frcp(dv);
            }
        }
    }
    block_atomic_add(lsum, &acc[3 + pair]);
}

__global__ void finalize_kernel(const double* __restrict__ acc,
                                float* __restrict__ out) {
    double l1 = (acc[0] + acc[1] + acc[2]) / (double)NEL;
    double ss = (acc[3] + acc[4] + acc[5]) /
                ((double)NSLICE * (double)VALID * (double)VALID);
    out[0] = (float)(3.0 + l1 - ss);
}

// host float -> fp16 bits, RNE (taps are normal-range)
static unsigned short f32_to_f16(float f) {
    unsigned u; memcpy(&u, &f, 4);
    unsigned s = (u >> 16) & 0x8000u;
    int e = (int)((u >> 23) & 0xff) - 127 + 15;
    unsigned m = u & 0x7fffffu;
    unsigned h = s | ((unsigned)e << 10) | (m >> 13);
    unsigned rem = m & 0x1fffu;
    if (rem > 0x1000u || (rem == 0x1000u && (h & 1))) h++;
    return (unsigned short)h;
}
static double f16_to_d(unsigned short h) {
    unsigned e = (h >> 10) & 0x1f, m = h & 0x3ffu;
    return ldexp((double)(m + 1024), (int)e - 25);
}

extern "C" void kernel_launch(void* const* d_in, const int* in_sizes, int n_in,
                              void* d_out, int out_size, void* d_ws, size_t ws_size,
                              hipStream_t stream) {
    const float* img = (const float*)d_in[0];
    const float* tgt = (const float*)d_in[1];
    const float* un  = (const float*)d_in[2];
    float* out = (float*)d_out;

    unsigned* pt1 = (unsigned*)d_ws;       // 33.5 MB each
    unsigned* pt2 = pt1 + NEL;
    double* acc = (double*)(pt2 + NEL);

    (void)hipMemsetAsync(acc, 0, 6 * sizeof(double), stream);

    // gaussian(11, 1.5) in double; renormalize so fp16 taps sum to ~1
    GH gh;
    {
        double g[11], s = 0.0;
        for (int i = 0; i < 11; ++i) { double d = i - 5; g[i] = exp(-d * d / 4.5); s += g[i]; }
        for (int i = 0; i < 11; ++i) g[i] /= s;
        for (int iter = 0; iter < 3; ++iter) {
            double sb = 0.0;
            unsigned short h[11];
            for (int i = 0; i < 11; ++i) { h[i] = f32_to_f16((float)g[i]); sb += f16_to_d(h[i]); }
            for (int i = 0; i < 11; ++i) { g[i] /= sb; gh.h[i] = (short)h[i]; }
        }
    }

    scan_kernel<<<2 * NPIX / 256, 256, 0, stream>>>(img, tgt, un, pt1, pt2, acc);
    ssim_kernel<<<dim3(16, NSLICE, 3), 256, 0, stream>>>(img, tgt, pt1, pt2, gh, acc);
    finalize_kernel<<<1, 1, 0, stream>>>(acc, out);
}

// Round 10
// 250.869 us; speedup vs baseline: 1.0119x; 1.0119x over previous
//
#include <hip/hip_runtime.h>
#include <cmath>
#include <cstring>

#define NUM_S   64
#define IMG_H   256
#define IMG_W   256
#define HWSZ    (IMG_H*IMG_W)          // 65536
#define BATCH   2
#define NPIX    (BATCH*HWSZ)           // 131072
#define NEL     (BATCH*NUM_S*HWSZ)     // 8388608
#define NSLICE  (BATCH*NUM_S)          // 128
#define VALID   246
#define EPS_F   1e-20f
#define C1_F    1e-4f
#define C2_F    9e-4f
#define RS      264                    // V_lds row stride (halves); 132 dw = 4 mod 32
#define FS      (16*RS)                // field size in halves = 4224
// slot layout in ws after pt arrays: [0,1024) scan L1, [1024,7168) ssim
#define NSLOT_SCAN 1024
#define NSLOT_ALL  7168

typedef __fp16 half8  __attribute__((ext_vector_type(8)));
typedef __fp16 fp16x2 __attribute__((ext_vector_type(2)));
using fragC = __attribute__((ext_vector_type(4))) float;  // 4 fp32

union H8 { half8 v; short s[8]; int i[4]; };
union PK { fp16x2 v; int i; };
union HS { __fp16 f; short s; };

struct GH { short h[11]; };            // fp16 bits of gaussian taps (sum ~= 1)

__device__ inline fp16x2 pkrtz(float a, float b) {
    return __builtin_amdgcn_cvt_pkrtz(a, b);   // 1 instr packs 2 values
}
__device__ inline float frcp(float x)  { return __builtin_amdgcn_rcpf(x); }
__device__ inline float flog2(float x) { return __builtin_amdgcn_logf(x); }   // v_log_f32
__device__ inline float fexp2(float x) { return __builtin_amdgcn_exp2f(x); }  // v_exp_f32

// block-reduce a float and WRITE to a unique slot (no init needed, no atomics)
__device__ inline void block_reduce_slot(float v, float* slot) {
    __shared__ float sm[8];
    __syncthreads();
    #pragma unroll
    for (int off = 32; off; off >>= 1) v += __shfl_down(v, off, 64);
    int lane = threadIdx.x & 63, w = threadIdx.x >> 6;
    if (lane == 0) sm[w] = v;
    __syncthreads();
    if (threadIdx.x == 0) {
        float s = 0.f;
        int nw = blockDim.x >> 6;
        for (int i = 0; i < nw; ++i) s += sm[i];
        *slot = s;
    }
}

// Kernel 1: per-pixel softmax-prefix scan, float2 (2 px/thread), prefetch
// depth 4 (12 loads in flight). No online max (e<=2e15, den<=1.3e17 fit
// fp32). Emits packed fp16 dwords: pt0={img,tgt} (fwd only), pt1/pt2={p,cummax}.
// L1 partial sums -> slots (no memset needed).
__global__ __launch_bounds__(256) void scan_kernel(
    const float* __restrict__ img, const float* __restrict__ tgt,
    const float* __restrict__ un,
    uint2* __restrict__ pt0, uint2* __restrict__ pt1, uint2* __restrict__ pt2,
    float* __restrict__ slots)
{
    const int HW2 = HWSZ / 2;               // 32768 float2 per slice
    int tid = blockIdx.x * 256 + threadIdx.x;
    bool bwd = tid >= (NPIX / 2);           // blocks 0..255 fwd, 256..511 bwd
    int p2 = bwd ? tid - NPIX / 2 : tid;
    int b   = p2 >> 15;
    int hw2 = p2 & (HW2 - 1);
    int idx  = b * (NUM_S * HW2) + hw2 + (bwd ? (NUM_S - 1) * HW2 : 0);
    int step = bwd ? -HW2 : HW2;
    const float2* __restrict__ img2 = (const float2*)img;
    const float2* __restrict__ tgt2 = (const float2*)tgt;
    const float2* __restrict__ un2  = (const float2*)un;

    float num[2] = {0.f, 0.f}, den[2] = {0.f, 0.f}, tm[2] = {-INFINITY, -INFINITY};
    float l1x = 0.f, l1p = 0.f;

    float2 xb[4], ub[4], tb[4];
    #pragma unroll
    for (int j = 0; j < 4; ++j) {
        int id = idx + j * step;
        xb[j] = img2[id]; ub[j] = un2[id]; tb[j] = tgt2[id];
    }

    for (int i = 0; i < NUM_S; ++i) {
        int buf = i & 3;
        float2 x = xb[buf], u = ub[buf], t = tb[buf];
        if (i + 4 < NUM_S) {                 // refill slot 4 slices ahead
            int id = idx + 4 * step;
            xb[buf] = img2[id]; ub[buf] = un2[id]; tb[buf] = tgt2[id];
        }
        float xc[2] = {x.x, x.y}, uc[2] = {u.x, u.y}, tc[2] = {t.x, t.y};
        float p[2];
        #pragma unroll
        for (int c = 0; c < 2; ++c) {
            // w = eps - ln(u+eps) > 0;  e = exp(2x) * w^-2
            float w = fmaf(flog2(uc[c] + EPS_F), -0.6931471805599453f, EPS_F);
            float r = frcp(w);
            float e = fexp2(xc[c] * 2.8853900817779268f) * (r * r);
            num[c] = fmaf(e, xc[c], num[c]);
            den[c] += e;
            p[c] = num[c] * frcp(den[c]);
            tm[c] = fmaxf(tm[c], tc[c]);
            if (!bwd) l1x += fabsf(xc[c] - tc[c]);
            l1p += fabsf(p[c] - tm[c]);
        }
        PK k0, k1;
        k0.v = pkrtz(p[0], tm[0]); k1.v = pkrtz(p[1], tm[1]);
        uint2 pv = make_uint2((unsigned)k0.i, (unsigned)k1.i);
        if (!bwd) {
            PK a0, a1;
            a0.v = pkrtz(xc[0], tc[0]); a1.v = pkrtz(xc[1], tc[1]);
            pt0[idx] = make_uint2((unsigned)a0.i, (unsigned)a1.i);
            pt1[idx] = pv;
        } else {
            pt2[idx] = pv;
        }
        idx += step;
    }
    block_reduce_slot(bwd ? 0.f : l1x, &slots[blockIdx.x]);
    block_reduce_slot(l1p, &slots[512 + blockIdx.x]);
}

// Kernel 2: MFMA separable-Gaussian SSIM, fp16 fragments, unified path:
// every pair reads a packed fp16 {a,b} dword image (pt0/pt1/pt2).
// Stage 1: ALL 32 loads issued upfront (R9's per-tile prefetch still paid
// ~4 serial latency rounds -- this pays one). D = band(16x32) . field-tile.
// V -> LDS fp16 (RS=264). Stage 2: D = A(V rows, b128) . band.
// Epilogue partials -> unique slots (no atomics/memset).
__global__ __launch_bounds__(256) void ssim_kernel(
    const unsigned* __restrict__ pt0, const unsigned* __restrict__ pt1,
    const unsigned* __restrict__ pt2,
    GH gh, float* __restrict__ slots)
{
    __shared__ short Vl[5][FS];            // 42240 B
    int pair  = blockIdx.z;
    int base  = blockIdx.y * HWSZ;
    int r0    = blockIdx.x * 16;
    int lane  = threadIdx.x & 63;
    int wid   = threadIdx.x >> 6;          // 0..3
    int q     = lane >> 4;                 // 0..3
    int n     = lane & 15;

    // band fragment: g[(q*8+j)-n], zero outside. A in stage 1, B in stage 2.
    H8 band;
    #pragma unroll
    for (int j = 0; j < 8; ++j) {
        int kk = q * 8 + j - n;
        short hv = 0;
        #pragma unroll
        for (int w = 0; w < 11; ++w) hv = (kk == w) ? gh.h[w] : hv;
        band.s[j] = hv;
    }

    // zero pad cols [256,264): 5 fields x 16 rows x 4 dwords = 320 dwords
    for (int d = threadIdx.x; d < 320; d += 256) {
        int f = d >> 6, rm = d & 63, r = rm >> 2, cc = rm & 3;
        ((int*)Vl)[f * 2112 + r * 132 + 128 + cc] = 0;
    }

    const unsigned* __restrict__ pp =
        (pair == 0 ? pt0 : (pair == 1 ? pt1 : pt2)) + base;
    bool clampR = (r0 == 240);
    const fragC zero = {0.f, 0.f, 0.f, 0.f};

    // ---- stage 1: all 32 loads upfront, then 4 c-tiles ----
    unsigned ld[32];
    {
        int rowbase = r0 + q * 8;
        if (!clampR) {
            const unsigned* pb = pp + rowbase * IMG_W + n;
            #pragma unroll
            for (int it = 0; it < 4; ++it)
                #pragma unroll
                for (int j = 0; j < 8; ++j)
                    ld[it * 8 + j] = pb[j * IMG_W + (wid * 4 + it) * 16];
        } else {
            #pragma unroll
            for (int it = 0; it < 4; ++it)
                #pragma unroll
                for (int j = 0; j < 8; ++j) {
                    int rr = min(rowbase + j, IMG_H - 1);
                    ld[it * 8 + j] = pp[rr * IMG_W + (wid * 4 + it) * 16 + n];
                }
        }
    }
    #pragma unroll
    for (int it = 0; it < 4; ++it) {
        H8 fX, fY, fXX, fYY, fXY;
        #pragma unroll
        for (int j = 0; j < 4; ++j) {          // {a(lo), b(hi)} merge
            unsigned a = ld[it * 8 + 2 * j], b2 = ld[it * 8 + 2 * j + 1];
            fX.i[j] = (int)((a & 0xffffu) | (b2 << 16));
            fY.i[j] = (int)((a >> 16) | (b2 & 0xffff0000u));
        }
        fXX.v = fX.v * fX.v;                   // v_pk_mul_f16
        fYY.v = fY.v * fY.v;
        fXY.v = fX.v * fY.v;
        fragC v0 = __builtin_amdgcn_mfma_f32_16x16x32_f16(band.v, fX.v,  zero, 0, 0, 0);
        fragC v1 = __builtin_amdgcn_mfma_f32_16x16x32_f16(band.v, fY.v,  zero, 0, 0, 0);
        fragC v2 = __builtin_amdgcn_mfma_f32_16x16x32_f16(band.v, fXX.v, zero, 0, 0, 0);
        fragC v3 = __builtin_amdgcn_mfma_f32_16x16x32_f16(band.v, fYY.v, zero, 0, 0, 0);
        fragC v4 = __builtin_amdgcn_mfma_f32_16x16x32_f16(band.v, fXY.v, zero, 0, 0, 0);
        int col = (wid * 4 + it) * 16 + n;
        #pragma unroll
        for (int reg = 0; reg < 4; ++reg) {
            int ro = (q * 4 + reg) * RS + col; // C-layout: row=q*4+reg, col=n
            HS cv;
            cv.f = (__fp16)v0[reg]; Vl[0][ro] = cv.s;
            cv.f = (__fp16)v1[reg]; Vl[1][ro] = cv.s;
            cv.f = (__fp16)v2[reg]; Vl[2][ro] = cv.s;
            cv.f = (__fp16)v3[reg]; Vl[3][ro] = cv.s;
            cv.f = (__fp16)v4[reg]; Vl[4][ro] = cv.s;
        }
    }
    __syncthreads();

    // ---- stage 2 + epilogue ----
    float lsum = 0.f;
    for (int it = 0; it < 4; ++it) {
        int c0 = (wid * 4 + it) * 16;
        int so = n * RS + c0 + q * 8;
        so = min(so, FS - 8);              // overreach only hits weight-zero k
        H8 a0, a1, a2, a3, a4;
        *(int4*)a0.i = *(const int4*)&Vl[0][so];
        *(int4*)a1.i = *(const int4*)&Vl[1][so];
        *(int4*)a2.i = *(const int4*)&Vl[2][so];
        *(int4*)a3.i = *(const int4*)&Vl[3][so];
        *(int4*)a4.i = *(const int4*)&Vl[4][so];
        fragC o0 = __builtin_amdgcn_mfma_f32_16x16x32_f16(a0.v, band.v, zero, 0, 0, 0);
        fragC o1 = __builtin_amdgcn_mfma_f32_16x16x32_f16(a1.v, band.v, zero, 0, 0, 0);
        fragC o2 = __builtin_amdgcn_mfma_f32_16x16x32_f16(a2.v, band.v, zero, 0, 0, 0);
        fragC o3 = __builtin_amdgcn_mfma_f32_16x16x32_f16(a3.v, band.v, zero, 0, 0, 0);
        fragC o4 = __builtin_amdgcn_mfma_f32_16x16x32_f16(a4.v, band.v, zero, 0, 0, 0);
        #pragma unroll
        for (int reg = 0; reg < 4; ++reg) {
            int r = r0 + q * 4 + reg;
            int c = c0 + n;
            if (r < VALID && c < VALID) {
                float m1 = o0[reg], m2 = o1[reg];
                float s11 = o2[reg] - m1 * m1;
                float s22 = o3[reg] - m2 * m2;
                float s12 = o4[reg] - m1 * m2;
                float nv = (2.f * m1 * m2 + C1_F) * (2.f * s12 + C2_F);
                float dv = (m1 * m1 + m2 * m2 + C1_F) * (s11 + s22 + C2_F);
                lsum += nv * frcp(dv);
            }
        }
    }
    block_reduce_slot(lsum,
        &slots[NSLOT_SCAN + pair * 2048 + blockIdx.y * 16 + blockIdx.x]);
}

__global__ void finalize_kernel(const float* __restrict__ slots,
                                float* __restrict__ out) {
    __shared__ double sa[4], sb[4];
    double a = 0.0, bsum = 0.0;
    for (int i = threadIdx.x; i < NSLOT_SCAN; i += 256) a += (double)slots[i];
    for (int i = NSLOT_SCAN + threadIdx.x; i < NSLOT_ALL; i += 256) bsum += (double)slots[i];
    #pragma unroll
    for (int off = 32; off; off >>= 1) {
        a    += __shfl_down(a, off, 64);
        bsum += __shfl_down(bsum, off, 64);
    }
    int lane = threadIdx.x & 63, w = threadIdx.x >> 6;
    if (lane == 0) { sa[w] = a; sb[w] = bsum; }
    __syncthreads();
    if (threadIdx.x == 0) {
        double A = sa[0] + sa[1] + sa[2] + sa[3];
        double B = sb[0] + sb[1] + sb[2] + sb[3];
        out[0] = (float)(3.0 + A / (double)NEL -
                         B / ((double)NSLICE * (double)VALID * (double)VALID));
    }
}

// host float -> fp16 bits, RNE (taps are normal-range)
static unsigned short f32_to_f16(float f) {
    unsigned u; memcpy(&u, &f, 4);
    unsigned s = (u >> 16) & 0x8000u;
    int e = (int)((u >> 23) & 0xff) - 127 + 15;
    unsigned m = u & 0x7fffffu;
    unsigned h = s | ((unsigned)e << 10) | (m >> 13);
    unsigned rem = m & 0x1fffu;
    if (rem > 0x1000u || (rem == 0x1000u && (h & 1))) h++;
    return (unsigned short)h;
}
static double f16_to_d(unsigned short h) {
    unsigned e = (h >> 10) & 0x1f, m = h & 0x3ffu;
    return ldexp((double)(m + 1024), (int)e - 25);
}

extern "C" void kernel_launch(void* const* d_in, const int* in_sizes, int n_in,
                              void* d_out, int out_size, void* d_ws, size_t ws_size,
                              hipStream_t stream) {
    const float* img = (const float*)d_in[0];
    const float* tgt = (const float*)d_in[1];
    const float* un  = (const float*)d_in[2];
    float* out = (float*)d_out;

    unsigned* pt0 = (unsigned*)d_ws;       // 33.5 MB each
    unsigned* pt1 = pt0 + NEL;
    unsigned* pt2 = pt1 + NEL;
    float* slots = (float*)(pt2 + NEL);    // 7168 floats, written not added

    // gaussian(11, 1.5) in double; renormalize so fp16 taps sum to ~1
    GH gh;
    {
        double g[11], s = 0.0;
        for (int i = 0; i < 11; ++i) { double d = i - 5; g[i] = exp(-d * d / 4.5); s += g[i]; }
        for (int i = 0; i < 11; ++i) g[i] /= s;
        for (int iter = 0; iter < 3; ++iter) {
            double sb = 0.0;
            unsigned short h[11];
            for (int i = 0; i < 11; ++i) { h[i] = f32_to_f16((float)g[i]); sb += f16_to_d(h[i]); }
            for (int i = 0; i < 11; ++i) { g[i] /= sb; gh.h[i] = (short)h[i]; }
        }
    }

    scan_kernel<<<NPIX / 256, 256, 0, stream>>>(img, tgt, un,
        (uint2*)pt0, (uint2*)pt1, (uint2*)pt2, slots);
    ssim_kernel<<<dim3(16, NSLICE, 3), 256, 0, stream>>>(pt0, pt1, pt2, gh, slots);
    finalize_kernel<<<1, 256, 0, stream>>>(slots, out);
}

// Round 11
// 201.167 us; speedup vs baseline: 1.2619x; 1.2471x over previous
//
#include <hip/hip_runtime.h>
#include <cmath>
#include <cstring>

#define NUM_S   64
#define IMG_H   256
#define IMG_W   256
#define HWSZ    (IMG_H*IMG_W)          // 65536
#define BATCH   2
#define NPIX    (BATCH*HWSZ)           // 131072
#define NEL     (BATCH*NUM_S*HWSZ)     // 8388608
#define NSLICE  (BATCH*NUM_S)          // 128
#define VALID   246
#define EPS_F   1e-20f
#define C1_F    1e-4f
#define C2_F    9e-4f
#define RS      264                    // V_lds row stride (halves); 132 dw = 4 mod 32
#define FS      (16*RS)                // field size in halves = 4224
// slot layout after pt arrays: [0,1024) scan L1, [1024,7168) ssim
#define NSLOT_SCAN 1024
#define NSLOT_ALL  7168
#define PTPAD   1024                   // 4 KB stagger between pt arrays (channel de-alias)

typedef __fp16 half8  __attribute__((ext_vector_type(8)));
typedef __fp16 fp16x2 __attribute__((ext_vector_type(2)));
using fragC = __attribute__((ext_vector_type(4))) float;  // 4 fp32

union H8 { half8 v; short s[8]; int i[4]; };
union PK { fp16x2 v; int i; };
union HS { __fp16 f; short s; };

struct GH { short h[11]; };            // fp16 bits of gaussian taps (sum ~= 1)

__device__ inline fp16x2 pkrtz(float a, float b) {
    return __builtin_amdgcn_cvt_pkrtz(a, b);   // 1 instr packs 2 values
}
__device__ inline float frcp(float x)  { return __builtin_amdgcn_rcpf(x); }
__device__ inline float flog2(float x) { return __builtin_amdgcn_logf(x); }   // v_log_f32
__device__ inline float fexp2(float x) { return __builtin_amdgcn_exp2f(x); }  // v_exp_f32

// block-reduce a float and WRITE to a unique slot (no init needed, no atomics)
__device__ inline void block_reduce_slot(float v, float* slot) {
    __shared__ float sm[8];
    __syncthreads();
    #pragma unroll
    for (int off = 32; off; off >>= 1) v += __shfl_down(v, off, 64);
    int lane = threadIdx.x & 63, w = threadIdx.x >> 6;
    if (lane == 0) sm[w] = v;
    __syncthreads();
    if (threadIdx.x == 0) {
        float s = 0.f;
        int nw = blockDim.x >> 6;
        for (int i = 0; i < nw; ++i) s += sm[i];
        *slot = s;
    }
}

// Kernel 1: per-pixel softmax-prefix scan, float2 (2 px/thread), depth-4
// prefetch with COMPILE-TIME buffer indices (R10's runtime `i&3` indexing
// demoted the buffers to scratch: VGPR_Count=28, +40MB HBM leak, 2.2TB/s).
// No online max (e<=2e15, den<=1.3e17 fit fp32). Emits packed fp16 dwords:
// pt0={img,tgt} (fwd only), pt1/pt2={p,cummax}. L1 partials -> slots.
__global__ __launch_bounds__(256) void scan_kernel(
    const float* __restrict__ img, const float* __restrict__ tgt,
    const float* __restrict__ un,
    uint2* __restrict__ pt0, uint2* __restrict__ pt1, uint2* __restrict__ pt2,
    float* __restrict__ slots)
{
    const int HW2 = HWSZ / 2;               // 32768 float2 per slice
    int tid = blockIdx.x * 256 + threadIdx.x;
    bool bwd = tid >= (NPIX / 2);           // blocks 0..255 fwd, 256..511 bwd
    int p2 = bwd ? tid - NPIX / 2 : tid;
    int b   = p2 >> 15;
    int hw2 = p2 & (HW2 - 1);
    int idx  = b * (NUM_S * HW2) + hw2 + (bwd ? (NUM_S - 1) * HW2 : 0);
    int step = bwd ? -HW2 : HW2;
    const float2* __restrict__ img2 = (const float2*)img;
    const float2* __restrict__ tgt2 = (const float2*)tgt;
    const float2* __restrict__ un2  = (const float2*)un;

    float num[2] = {0.f, 0.f}, den[2] = {0.f, 0.f}, tm[2] = {-INFINITY, -INFINITY};
    float l1x = 0.f, l1p = 0.f;

    float2 xb[4], ub[4], tb[4];
    #pragma unroll
    for (int j = 0; j < 4; ++j) {
        int id = idx + j * step;
        xb[j] = img2[id]; ub[j] = un2[id]; tb[j] = tgt2[id];
    }

    for (int i = 0; i < NUM_S; i += 4) {
        #pragma unroll
        for (int j = 0; j < 4; ++j) {        // j is compile-time constant
            float2 x = xb[j], u = ub[j], t = tb[j];
            if (i + j + 4 < NUM_S) {         // refill slot 4 slices ahead
                int id = idx + 4 * step;
                xb[j] = img2[id]; ub[j] = un2[id]; tb[j] = tgt2[id];
            }
            float xc[2] = {x.x, x.y}, uc[2] = {u.x, u.y}, tc[2] = {t.x, t.y};
            float p[2];
            #pragma unroll
            for (int c = 0; c < 2; ++c) {
                // w = eps - ln(u+eps) > 0;  e = exp(2x) * w^-2
                float w = fmaf(flog2(uc[c] + EPS_F), -0.6931471805599453f, EPS_F);
                float r = frcp(w);
                float e = fexp2(xc[c] * 2.8853900817779268f) * (r * r);
                num[c] = fmaf(e, xc[c], num[c]);
                den[c] += e;
                p[c] = num[c] * frcp(den[c]);
                tm[c] = fmaxf(tm[c], tc[c]);
                if (!bwd) l1x += fabsf(xc[c] - tc[c]);
                l1p += fabsf(p[c] - tm[c]);
            }
            PK k0, k1;
            k0.v = pkrtz(p[0], tm[0]); k1.v = pkrtz(p[1], tm[1]);
            uint2 pv = make_uint2((unsigned)k0.i, (unsigned)k1.i);
            if (!bwd) {
                PK a0, a1;
                a0.v = pkrtz(xc[0], tc[0]); a1.v = pkrtz(xc[1], tc[1]);
                pt0[idx] = make_uint2((unsigned)a0.i, (unsigned)a1.i);
                pt1[idx] = pv;
            } else {
                pt2[idx] = pv;
            }
            idx += step;
        }
    }
    block_reduce_slot(bwd ? 0.f : l1x, &slots[blockIdx.x]);
    block_reduce_slot(l1p, &slots[512 + blockIdx.x]);
}

// Kernel 2: MFMA separable-Gaussian SSIM, fp16 fragments, unified path:
// every pair reads a packed fp16 {a,b} dword image (pt0/pt1/pt2).
// Stage 1: all 32 loads upfront (one latency exposure). D = band(16x32) .
// field-tile. V -> LDS fp16 (RS=264). Stage 2: D = A(V rows, b128) . band.
// Epilogue partials -> unique slots (no atomics/memset).
__global__ __launch_bounds__(256) void ssim_kernel(
    const unsigned* __restrict__ pt0, const unsigned* __restrict__ pt1,
    const unsigned* __restrict__ pt2,
    GH gh, float* __restrict__ slots)
{
    __shared__ short Vl[5][FS];            // 42240 B
    int pair  = blockIdx.z;
    int base  = blockIdx.y * HWSZ;
    int r0    = blockIdx.x * 16;
    int lane  = threadIdx.x & 63;
    int wid   = threadIdx.x >> 6;          // 0..3
    int q     = lane >> 4;                 // 0..3
    int n     = lane & 15;

    // band fragment: g[(q*8+j)-n], zero outside. A in stage 1, B in stage 2.
    H8 band;
    #pragma unroll
    for (int j = 0; j < 8; ++j) {
        int kk = q * 8 + j - n;
        short hv = 0;
        #pragma unroll
        for (int w = 0; w < 11; ++w) hv = (kk == w) ? gh.h[w] : hv;
        band.s[j] = hv;
    }

    // zero pad cols [256,264): 5 fields x 16 rows x 4 dwords = 320 dwords
    for (int d = threadIdx.x; d < 320; d += 256) {
        int f = d >> 6, rm = d & 63, r = rm >> 2, cc = rm & 3;
        ((int*)Vl)[f * 2112 + r * 132 + 128 + cc] = 0;
    }

    const unsigned* __restrict__ pp =
        (pair == 0 ? pt0 : (pair == 1 ? pt1 : pt2)) + base;
    bool clampR = (r0 == 240);
    const fragC zero = {0.f, 0.f, 0.f, 0.f};

    // ---- stage 1: all 32 loads upfront, then 4 c-tiles ----
    unsigned ld[32];
    {
        int rowbase = r0 + q * 8;
        if (!clampR) {
            const unsigned* pb = pp + rowbase * IMG_W + n;
            #pragma unroll
            for (int it = 0; it < 4; ++it)
                #pragma unroll
                for (int j = 0; j < 8; ++j)
                    ld[it * 8 + j] = pb[j * IMG_W + (wid * 4 + it) * 16];
        } else {
            #pragma unroll
            for (int it = 0; it < 4; ++it)
                #pragma unroll
                for (int j = 0; j < 8; ++j) {
                    int rr = min(rowbase + j, IMG_H - 1);
                    ld[it * 8 + j] = pp[rr * IMG_W + (wid * 4 + it) * 16 + n];
                }
        }
    }
    #pragma unroll
    for (int it = 0; it < 4; ++it) {
        H8 fX, fY, fXX, fYY, fXY;
        #pragma unroll
        for (int j = 0; j < 4; ++j) {          // {a(lo), b(hi)} merge
            unsigned a = ld[it * 8 + 2 * j], b2 = ld[it * 8 + 2 * j + 1];
            fX.i[j] = (int)((a & 0xffffu) | (b2 << 16));
            fY.i[j] = (int)((a >> 16) | (b2 & 0xffff0000u));
        }
        fXX.v = fX.v * fX.v;                   // v_pk_mul_f16
        fYY.v = fY.v * fY.v;
        fXY.v = fX.v * fY.v;
        fragC v0 = __builtin_amdgcn_mfma_f32_16x16x32_f16(band.v, fX.v,  zero, 0, 0, 0);
        fragC v1 = __builtin_amdgcn_mfma_f32_16x16x32_f16(band.v, fY.v,  zero, 0, 0, 0);
        fragC v2 = __builtin_amdgcn_mfma_f32_16x16x32_f16(band.v, fXX.v, zero, 0, 0, 0);
        fragC v3 = __builtin_amdgcn_mfma_f32_16x16x32_f16(band.v, fYY.v, zero, 0, 0, 0);
        fragC v4 = __builtin_amdgcn_mfma_f32_16x16x32_f16(band.v, fXY.v, zero, 0, 0, 0);
        int col = (wid * 4 + it) * 16 + n;
        #pragma unroll
        for (int reg = 0; reg < 4; ++reg) {
            int ro = (q * 4 + reg) * RS + col; // C-layout: row=q*4+reg, col=n
            HS cv;
            cv.f = (__fp16)v0[reg]; Vl[0][ro] = cv.s;
            cv.f = (__fp16)v1[reg]; Vl[1][ro] = cv.s;
            cv.f = (__fp16)v2[reg]; Vl[2][ro] = cv.s;
            cv.f = (__fp16)v3[reg]; Vl[3][ro] = cv.s;
            cv.f = (__fp16)v4[reg]; Vl[4][ro] = cv.s;
        }
    }
    __syncthreads();

    // ---- stage 2 + epilogue ----
    float lsum = 0.f;
    for (int it = 0; it < 4; ++it) {
        int c0 = (wid * 4 + it) * 16;
        int so = n * RS + c0 + q * 8;
        so = min(so, FS - 8);              // overreach only hits weight-zero k
        H8 a0, a1, a2, a3, a4;
        *(int4*)a0.i = *(const int4*)&Vl[0][so];
        *(int4*)a1.i = *(const int4*)&Vl[1][so];
        *(int4*)a2.i = *(const int4*)&Vl[2][so];
        *(int4*)a3.i = *(const int4*)&Vl[3][so];
        *(int4*)a4.i = *(const int4*)&Vl[4][so];
        fragC o0 = __builtin_amdgcn_mfma_f32_16x16x32_f16(a0.v, band.v, zero, 0, 0, 0);
        fragC o1 = __builtin_amdgcn_mfma_f32_16x16x32_f16(a1.v, band.v, zero, 0, 0, 0);
        fragC o2 = __builtin_amdgcn_mfma_f32_16x16x32_f16(a2.v, band.v, zero, 0, 0, 0);
        fragC o3 = __builtin_amdgcn_mfma_f32_16x16x32_f16(a3.v, band.v, zero, 0, 0, 0);
        fragC o4 = __builtin_amdgcn_mfma_f32_16x16x32_f16(a4.v, band.v, zero, 0, 0, 0);
        #pragma unroll
        for (int reg = 0; reg < 4; ++reg) {
            int r = r0 + q * 4 + reg;
            int c = c0 + n;
            if (r < VALID && c < VALID) {
                float m1 = o0[reg], m2 = o1[reg];
                float s11 = o2[reg] - m1 * m1;
                float s22 = o3[reg] - m2 * m2;
                float s12 = o4[reg] - m1 * m2;
                float nv = (2.f * m1 * m2 + C1_F) * (2.f * s12 + C2_F);
                float dv = (m1 * m1 + m2 * m2 + C1_F) * (s11 + s22 + C2_F);
                lsum += nv * frcp(dv);
            }
        }
    }
    block_reduce_slot(lsum,
        &slots[NSLOT_SCAN + pair * 2048 + blockIdx.y * 16 + blockIdx.x]);
}

__global__ void finalize_kernel(const float* __restrict__ slots,
                                float* __restrict__ out) {
    __shared__ double sa[4], sb[4];
    double a = 0.0, bsum = 0.0;
    for (int i = threadIdx.x; i < NSLOT_SCAN; i += 256) a += (double)slots[i];
    for (int i = NSLOT_SCAN + threadIdx.x; i < NSLOT_ALL; i += 256) bsum += (double)slots[i];
    #pragma unroll
    for (int off = 32; off; off >>= 1) {
        a    += __shfl_down(a, off, 64);
        bsum += __shfl_down(bsum, off, 64);
    }
    int lane = threadIdx.x & 63, w = threadIdx.x >> 6;
    if (lane == 0) { sa[w] = a; sb[w] = bsum; }
    __syncthreads();
    if (threadIdx.x == 0) {
        double A = sa[0] + sa[1] + sa[2] + sa[3];
        double B = sb[0] + sb[1] + sb[2] + sb[3];
        out[0] = (float)(3.0 + A / (double)NEL -
                         B / ((double)NSLICE * (double)VALID * (double)VALID));
    }
}

// host float -> fp16 bits, RNE (taps are normal-range)
static unsigned short f32_to_f16(float f) {
    unsigned u; memcpy(&u, &f, 4);
    unsigned s = (u >> 16) & 0x8000u;
    int e = (int)((u >> 23) & 0xff) - 127 + 15;
    unsigned m = u & 0x7fffffu;
    unsigned h = s | ((unsigned)e << 10) | (m >> 13);
    unsigned rem = m & 0x1fffu;
    if (rem > 0x1000u || (rem == 0x1000u && (h & 1))) h++;
    return (unsigned short)h;
}
static double f16_to_d(unsigned short h) {
    unsigned e = (h >> 10) & 0x1f, m = h & 0x3ffu;
    return ldexp((double)(m + 1024), (int)e - 25);
}

extern "C" void kernel_launch(void* const* d_in, const int* in_sizes, int n_in,
                              void* d_out, int out_size, void* d_ws, size_t ws_size,
                              hipStream_t stream) {
    const float* img = (const float*)d_in[0];
    const float* tgt = (const float*)d_in[1];
    const float* un  = (const float*)d_in[2];
    float* out = (float*)d_out;

    unsigned* pt0 = (unsigned*)d_ws;               // 33.5 MB each, staggered
    unsigned* pt1 = pt0 + NEL + PTPAD;             // +4 KB phase shift
    unsigned* pt2 = pt1 + NEL + PTPAD;
    float* slots = (float*)(pt2 + NEL);            // 7168 floats, written not added

    // gaussian(11, 1.5) in double; renormalize so fp16 taps sum to ~1
    GH gh;
    {
        double g[11], s = 0.0;
        for (int i = 0; i < 11; ++i) { double d = i - 5; g[i] = exp(-d * d / 4.5); s += g[i]; }
        for (int i = 0; i < 11; ++i) g[i] /= s;
        for (int iter = 0; iter < 3; ++iter) {
            double sb = 0.0;
            unsigned short h[11];
            for (int i = 0; i < 11; ++i) { h[i] = f32_to_f16((float)g[i]); sb += f16_to_d(h[i]); }
            for (int i = 0; i < 11; ++i) { g[i] /= sb; gh.h[i] = (short)h[i]; }
        }
    }

    scan_kernel<<<NPIX / 256, 256, 0, stream>>>(img, tgt, un,
        (uint2*)pt0, (uint2*)pt1, (uint2*)pt2, slots);
    ssim_kernel<<<dim3(16, NSLICE, 3), 256, 0, stream>>>(pt0, pt1, pt2, gh, slots);
    finalize_kernel<<<1, 256, 0, stream>>>(slots, out);
}